// Round 1
// baseline (235.857 us; speedup 1.0000x reference)
//
#include <hip/hip_runtime.h>

// Izhikevich spiking neuron scan, time-chunked, float4-vectorized with an
// explicit 8-deep register prefetch pipeline.
//
// x: [T=512, N=65536] f32. out: [T, N] f32 spike train (0.0 / 1.0).
//
// Recurrence per neuron (expression kept bit-identical to the verified
// scalar kernel — absmax 0.0):
//   v = (4v^2 + 5v + 1.4 - r + x_t) * DT   (DT = 1/512)
//   r = 0.02 * (0.2v - v) * DT             (uses NEW v)
//   fire = v >= 0.3 ; fire -> v = -0.065, r += 0.008 ; out_t = fire
//
// Time-split justification (unchanged): the map contracts prior state by
// ~(5/512) per step, so 8 warmup steps shrink any init-state error below
// fp32 ulp; the output bit (v >= 0.3) is insensitive regardless.
//
// Round-1 change: previous kernel was latency-bound (VALUBusy 18%, HBM 31%
// of peak, VGPR_Count=20 => only ~1-2 loads in flight per wave despite
// "#pragma unroll 8"). Fix: 4 neurons/thread via float4 (16 B/lane, 4
// independent recurrence chains) + explicit buf[8] register pipeline with
// static indices (reload buf[i] immediately after consuming it), giving
// 8 x 1 KB outstanding loads per wave. Grid: 64 x 8 = 512 blocks = 2
// blocks/CU (8 waves/CU) — 64 KB/CU of reads in flight, well above the
// ~10 KB needed to cover ~900 cyc HBM latency at full bandwidth.

#define T_STEPS 512
#define N_NEUR  65536
#define N4      (N_NEUR / 4)     // 16384 float4 columns
#define DT      (1.0f / 512.0f)
#define TCH     64               // timesteps written per chunk (512/8)
#define WARM    8                // warmup steps to converge state at chunk start
#define NP      8                // prefetch depth (timesteps in flight)
#define NBLK    (TCH / NP)       // 8 pipeline blocks per chunk

__device__ __forceinline__ float izi_step(float xt, float& v, float& r) {
    v = (4.0f * v * v + 5.0f * v + 1.4f - r + xt) * DT;
    r = 0.02f * (0.2f * v - v) * DT;
    const bool fire = v >= 0.3f;
    if (fire) { v = -0.065f; r += 0.008f; }
    return fire ? 1.0f : 0.0f;
}

__device__ __forceinline__ float4 izi_step4(const float4 xt, float4& v, float4& r) {
    float4 o;
    o.x = izi_step(xt.x, v.x, r.x);
    o.y = izi_step(xt.y, v.y, r.y);
    o.z = izi_step(xt.z, v.z, r.z);
    o.w = izi_step(xt.w, v.w, r.w);
    return o;
}

__global__ __launch_bounds__(256, 2) void izi_kernel(const float4* __restrict__ x,
                                                     float4* __restrict__ out) {
    const int col = blockIdx.x * 256 + threadIdx.x;  // float4 column, coalesced
    const int c = blockIdx.y;                        // time chunk 0..7
    const int tstart = c * TCH;

    float4 v = make_float4(-0.065f, -0.065f, -0.065f, -0.065f);
    float4 r = make_float4(0.0f, 0.0f, 0.0f, 0.0f);

    if (c > 0) {
        // Warmup: addresses are state-independent; full unroll lets the
        // compiler batch these 8 loads.
        #pragma unroll
        for (int t = tstart - WARM; t < tstart; ++t) {
            const float4 xt = x[(size_t)t * N4 + col];
            (void)izi_step4(xt, v, r);
        }
    }

    // Prime the pipeline: 8 timesteps of this chunk in flight.
    float4 buf[NP];
    #pragma unroll
    for (int i = 0; i < NP; ++i)
        buf[i] = x[(size_t)(tstart + i) * N4 + col];

    // Steady state: consume buf[i], immediately reissue the load for the
    // same slot NP steps ahead. Inner loop fully unrolled so every buf
    // index is compile-time constant (registers, not scratch).
    for (int tb = 0; tb < NBLK - 1; ++tb) {
        const int t0 = tstart + tb * NP;
        #pragma unroll
        for (int i = 0; i < NP; ++i) {
            const float4 xt = buf[i];
            buf[i] = x[(size_t)(t0 + NP + i) * N4 + col];   // prefetch
            out[(size_t)(t0 + i) * N4 + col] = izi_step4(xt, v, r);
        }
    }

    // Drain: last block, no reload.
    {
        const int t0 = tstart + TCH - NP;
        #pragma unroll
        for (int i = 0; i < NP; ++i) {
            out[(size_t)(t0 + i) * N4 + col] = izi_step4(buf[i], v, r);
        }
    }
}

extern "C" void kernel_launch(void* const* d_in, const int* in_sizes, int n_in,
                              void* d_out, int out_size, void* d_ws, size_t ws_size,
                              hipStream_t stream) {
    const float4* x = (const float4*)d_in[0];
    float4* out = (float4*)d_out;
    // grid: 64 neuron-blocks x 8 time-chunks = 512 blocks (2 per CU).
    izi_kernel<<<dim3(N4 / 256, T_STEPS / TCH), dim3(256), 0, stream>>>(x, out);
}

// Round 2
// 224.313 us; speedup vs baseline: 1.0515x; 1.0515x over previous
//
#include <hip/hip_runtime.h>

// Izhikevich spiking neuron scan, time-chunked, float2-vectorized with a
// ping-pong 8-deep register prefetch pipeline pinned by sched_barrier.
//
// x: [T=512, N=65536] f32. out: [T, N] f32 spike train (0.0 / 1.0).
//
// Recurrence per neuron (expression bit-identical to the verified kernels):
//   v = (4v^2 + 5v + 1.4 - r + x_t) * DT   (DT = 1/512)
//   r = 0.02 * (0.2v - v) * DT             (uses NEW v)
//   fire = v >= 0.3 ; fire -> v = -0.065, r += 0.008 ; out_t = fire
//
// Time-split justification: the map contracts prior state by ~(5/512) per
// step; 8 warmup steps shrink any init-state error by ~1e-16, below fp32
// ulp. Verified absmax=0.0 across two prior mappings.
//
// Round-2 theory: round 1 kept HBM at 2.5 TB/s because the grid shrank 4x
// (8 waves/CU) while per-wave MLP didn't grow (allocator sank the reloads;
// VGPR=48). Latency hiding needs waves x in-flight-bytes: BW*latency ~
// 11 KB/CU of reads. This version restores 2048 blocks (8 blocks/CU,
// 32 waves/CU) via TCH=32 x 16 chunks, uses float2 (small buf, allocator
// slack), batches 8 loads per tile into a ping-pong buf[2][8] (fully
// unrolled, static indices), and pins the batch above the compute with
// __builtin_amdgcn_sched_barrier(0). Steady state: 32 waves/CU x 4 KB
// in flight = 128 KB/CU >> 11 KB. Stores are non-temporal: the output is
// never re-read, and NT keeps the input resident in L2/L3 (round 0 showed
// L3 absorbing ~55 MB of reads).

#define T_STEPS 512
#define N_NEUR  65536
#define N2      (N_NEUR / 2)     // 32768 float2 columns
#define DT      (1.0f / 512.0f)
#define TCH     32               // timesteps per chunk (512/16)
#define WARM    8                // warmup steps to converge state at chunk start
#define NP      8                // prefetch batch depth (timesteps per tile)
#define NBLK    (TCH / NP)       // 4 tiles per chunk

typedef float v2f __attribute__((ext_vector_type(2)));

__device__ __forceinline__ float izi_step(float xt, float& v, float& r) {
    v = (4.0f * v * v + 5.0f * v + 1.4f - r + xt) * DT;
    r = 0.02f * (0.2f * v - v) * DT;
    const bool fire = v >= 0.3f;
    if (fire) { v = -0.065f; r += 0.008f; }
    return fire ? 1.0f : 0.0f;
}

__device__ __forceinline__ v2f izi_step2(const v2f xt, v2f& v, v2f& r) {
    v2f o;
    float vx = v.x, rx = r.x, vy = v.y, ry = r.y;
    o.x = izi_step(xt.x, vx, rx);
    o.y = izi_step(xt.y, vy, ry);
    v.x = vx; r.x = rx; v.y = vy; r.y = ry;
    return o;
}

__global__ __launch_bounds__(256, 4) void izi_kernel(const v2f* __restrict__ x,
                                                     v2f* __restrict__ out) {
    const int col = blockIdx.x * 256 + threadIdx.x;  // float2 column, coalesced
    const int c = blockIdx.y;                        // time chunk 0..15
    const int tstart = c * TCH;

    v2f v; v.x = -0.065f; v.y = -0.065f;
    v2f r; r.x = 0.0f;    r.y = 0.0f;

    if (c > 0) {
        // Warmup: addresses state-independent; full unroll batches the loads.
        #pragma unroll
        for (int t = tstart - WARM; t < tstart; ++t) {
            const v2f xt = x[(size_t)t * N2 + col];
            (void)izi_step2(xt, v, r);
        }
    }

    // Ping-pong pipeline: buf[2][NP], fully unrolled so every index is
    // compile-time constant (registers, not scratch).
    v2f buf[2][NP];
    #pragma unroll
    for (int i = 0; i < NP; ++i)
        buf[0][i] = x[(size_t)(tstart + i) * N2 + col];

    #pragma unroll
    for (int tb = 0; tb < NBLK; ++tb) {
        const int cur = tb & 1;
        const int nxt = cur ^ 1;
        const int t0 = tstart + tb * NP;

        if (tb < NBLK - 1) {
            // Batch-issue next tile's 8 loads before touching this tile.
            #pragma unroll
            for (int i = 0; i < NP; ++i)
                buf[nxt][i] = x[(size_t)(t0 + NP + i) * N2 + col];
        }
        // Pin: nothing below may be hoisted above, nothing above may sink.
        __builtin_amdgcn_sched_barrier(0);

        #pragma unroll
        for (int i = 0; i < NP; ++i) {
            const v2f o = izi_step2(buf[cur][i], v, r);
            __builtin_nontemporal_store(o, &out[(size_t)(t0 + i) * N2 + col]);
        }
    }
}

extern "C" void kernel_launch(void* const* d_in, const int* in_sizes, int n_in,
                              void* d_out, int out_size, void* d_ws, size_t ws_size,
                              hipStream_t stream) {
    const v2f* x = (const v2f*)d_in[0];
    v2f* out = (v2f*)d_out;
    // grid: 128 neuron-blocks x 16 time-chunks = 2048 blocks (8 per CU,
    // 32 waves/CU — full wave-slot occupancy at VGPR<=64).
    izi_kernel<<<dim3(N2 / 256, T_STEPS / TCH), dim3(256), 0, stream>>>(x, out);
}